// Round 1
// baseline (461.938 us; speedup 1.0000x reference)
//
#include <hip/hip_runtime.h>
#include <hip/hip_bf16.h>
#include <math.h>

// ---------------------------------------------------------------------------
// SO8T rotation gate: y[b,t,n,:] = x[b,t,n,:] @ R[n],  R[n] = scale-square
// Taylor expm of A[n] = theta[n] - theta[n]^T, faithful to reference
// (per-block s, but ALL blocks squared max_s times, EPS spots included).
// ---------------------------------------------------------------------------

#define MAX_ITER 12
#define EPS 1e-7f
#define SQ_CAP 8
#define ROWS_PER_BLOCK 32

// Kernel 1: compute max_s over all blocks (single workgroup).
__global__ __launch_bounds__(512) void smax_kernel(const float* __restrict__ theta,
                                                   int* __restrict__ maxs,
                                                   int num_blocks) {
    __shared__ int sm[512];
    int tid = threadIdx.x;
    int s_i = 0;
    if (tid < num_blocks) {
        const float* tb = theta + (size_t)tid * 64;
        float n2 = 0.0f;
        #pragma unroll
        for (int i = 0; i < 8; ++i)
            #pragma unroll
            for (int j = 0; j < 8; ++j) {
                float a = tb[i * 8 + j] - tb[j * 8 + i];
                n2 = fmaf(a, a, n2);
            }
        float norm = sqrtf(n2);
        float s = ceilf(log2f(norm + EPS));
        if (s < 0.0f) s = 0.0f;
        s_i = (int)s;
    }
    sm[tid] = s_i;
    __syncthreads();
    for (int off = 256; off > 0; off >>= 1) {
        if (tid < off && tid + off < 512) sm[tid] = max(sm[tid], sm[tid + off]);
        __syncthreads();
    }
    if (tid == 0) maxs[0] = sm[0];
}

// Kernel 2: per-block expm. One workgroup (1 wave, 64 lanes) per 8x8 block;
// lane (i,j) owns entry [i][j].
__global__ __launch_bounds__(64) void expm_kernel(const float* __restrict__ theta,
                                                  const int* __restrict__ maxs,
                                                  float* __restrict__ Rbuf) {
    const int n = blockIdx.x;
    const int lane = threadIdx.x;
    const int i = lane >> 3, j = lane & 7;
    const float* tb = theta + (size_t)n * 64;
    float a = tb[i * 8 + j] - tb[j * 8 + i];

    // Frobenius norm^2 over the 64 entries (wave reduction).
    float n2 = a * a;
    #pragma unroll
    for (int off = 32; off >= 1; off >>= 1) n2 += __shfl_xor(n2, off, 64);

    float norm = sqrtf(n2);
    float s = ceilf(log2f(norm + EPS));
    if (s < 0.0f) s = 0.0f;
    float scale = exp2f(s);
    float as = a / (scale + EPS);

    __shared__ float As[64];
    __shared__ float Ap[64];
    As[lane] = as;

    float R = (i == j) ? 1.0f : 0.0f;
    float Apow = as;
    float fact = 1.0f;
    __syncthreads();

    for (int it = 1; it <= MAX_ITER; ++it) {
        fact *= (float)it;
        R += Apow / fact;
        if (it < MAX_ITER) {
            Ap[lane] = Apow;
            __syncthreads();
            float t = 0.0f;
            #pragma unroll
            for (int k = 0; k < 8; ++k) t = fmaf(Ap[i * 8 + k], As[k * 8 + j], t);
            __syncthreads();
            Apow = t;
        }
    }

    int ms = maxs[0];
    if (ms > SQ_CAP) ms = SQ_CAP;
    for (int k2 = 0; k2 < ms; ++k2) {
        Ap[lane] = R;
        __syncthreads();
        float t = 0.0f;
        #pragma unroll
        for (int k = 0; k < 8; ++k) t = fmaf(Ap[i * 8 + k], Ap[k * 8 + j], t);
        __syncthreads();
        R = t;
    }
    Rbuf[(size_t)n * 64 + lane] = R;
}

// Kernel 3: streaming apply. Each thread owns one n-block (R[n] in registers)
// and processes ROWS_PER_BLOCK rows. Wave = 64 consecutive n -> 2 KB
// contiguous per row; float4 loads/stores.
__global__ __launch_bounds__(256) void apply_kernel(const float* __restrict__ x,
                                                    const float* __restrict__ Rbuf,
                                                    float* __restrict__ y,
                                                    int D) {
    const int tid = threadIdx.x;
    const int n = blockIdx.y * 256 + tid;      // block-column index
    const int r0 = blockIdx.x * ROWS_PER_BLOCK;

    // Load R[n] (64 floats) into registers.
    float r[64];
    const float4* Rp = (const float4*)(Rbuf + (size_t)n * 64);
    #pragma unroll
    for (int q = 0; q < 16; ++q) {
        float4 v = Rp[q];
        r[q * 4 + 0] = v.x; r[q * 4 + 1] = v.y;
        r[q * 4 + 2] = v.z; r[q * 4 + 3] = v.w;
    }

    const float* xp = x + (size_t)r0 * D + (size_t)n * 8;
    float*       yp = y + (size_t)r0 * D + (size_t)n * 8;

    #pragma unroll 2
    for (int k = 0; k < ROWS_PER_BLOCK; ++k) {
        float4 x0 = *(const float4*)(xp);
        float4 x1 = *(const float4*)(xp + 4);
        float xe[8] = {x0.x, x0.y, x0.z, x0.w, x1.x, x1.y, x1.z, x1.w};
        float yo[8];
        #pragma unroll
        for (int o = 0; o < 8; ++o) {
            float acc = xe[0] * r[o];
            #pragma unroll
            for (int e = 1; e < 8; ++e) acc = fmaf(xe[e], r[e * 8 + o], acc);
            yo[o] = acc;
        }
        float4 y0 = {yo[0], yo[1], yo[2], yo[3]};
        float4 y1 = {yo[4], yo[5], yo[6], yo[7]};
        *(float4*)(yp)     = y0;
        *(float4*)(yp + 4) = y1;
        xp += D;
        yp += D;
    }
}

extern "C" void kernel_launch(void* const* d_in, const int* in_sizes, int n_in,
                              void* d_out, int out_size, void* d_ws, size_t ws_size,
                              hipStream_t stream) {
    const float* x     = (const float*)d_in[0];
    const float* theta = (const float*)d_in[1];
    float* y = (float*)d_out;

    const int tsize = in_sizes[1];
    const int num_blocks = tsize / 64;          // 512
    const int D = num_blocks * 8;               // 4096
    const long rows = (long)in_sizes[0] / D;    // B*T = 16384

    float* Rbuf = (float*)d_ws;
    int*   maxs = (int*)((char*)d_ws + (size_t)num_blocks * 64 * sizeof(float));

    smax_kernel<<<1, 512, 0, stream>>>(theta, maxs, num_blocks);
    expm_kernel<<<num_blocks, 64, 0, stream>>>(theta, maxs, Rbuf);

    dim3 grid((unsigned)(rows / ROWS_PER_BLOCK), (unsigned)(num_blocks / 256));
    apply_kernel<<<grid, 256, 0, stream>>>(x, Rbuf, y, D);
}